// Round 10
// baseline (427.091 us; speedup 1.0000x reference)
//
#include <hip/hip_runtime.h>

#define NN 16384
#define DD 16
#define KK 64
#define QQ 4            // queries per block (share x_j loads; fit SGPR file)
#define TPB 512
#define HIST 1024       // buckets over d2 in [0,256), width 1/4 — covers ALL pairs
#define LIST_MAX 1024   // expected ~600 entries, +17 sigma margin
#define CAND_MAX 256

// XLA:CPU vectorized row-reduce, minor dim 16: lane halving tree. (VALIDATED r5)
__device__ __forceinline__ float halving_sumsq16(const float* v) {
    float p[16];
#pragma unroll
    for (int d = 0; d < 16; ++d) p[d] = __fmul_rn(v[d], v[d]);
    float r8[8];
#pragma unroll
    for (int j = 0; j < 8; ++j) r8[j] = __fadd_rn(p[j], p[j + 8]);
    float r4[4];
#pragma unroll
    for (int j = 0; j < 4; ++j) r4[j] = __fadd_rn(r8[j], r8[j + 4]);
    float r2[2];
#pragma unroll
    for (int j = 0; j < 2; ++j) r2[j] = __fadd_rn(r4[j], r4[j + 2]);
    return __fadd_rn(r2[0], r2[1]);
}

// d2 recipe (VALIDATED r5): f32( f32(sqi+sqj) - 2*dot ), dot = ascending-k fmaf
__device__ __forceinline__ float d2_of(const float* xi, const float* xj,
                                       float sqi, float sqj) {
    float dot = 0.0f;
#pragma unroll
    for (int d = 0; d < DD; ++d) dot = fmaf(xi[d], xj[d], dot);
    return __fsub_rn(__fadd_rn(sqi, sqj), __fmul_rn(2.0f, dot));
}

__device__ __forceinline__ int bucket_of(float d2) {   // used by E, D, G identically
    int b = (int)__fmul_rn(d2, 4.0f);
    if (b < 0) b = 0;
    if (b >= HIST) b = HIST - 1;
    return b;
}

// ---------------- prep: f32 squared norms (halving tree) + copy x ----------------
__global__ void prep_kernel(const float* __restrict__ x,
                            float* __restrict__ out_x,
                            float* __restrict__ sqf) {
    int i = blockIdx.x * blockDim.x + threadIdx.x;
    if (i < NN) {
        float v[DD];
#pragma unroll
        for (int d = 0; d < DD; ++d) v[d] = x[i * DD + d];
        sqf[i] = halving_sumsq16(v);
    }
    for (int t = i; t < NN * DD; t += gridDim.x * blockDim.x) {
        out_x[t] = x[t];
    }
}

// ---------------- main: 4 queries/block, 512 threads, single scan + adaptive list ----------------
__global__ __launch_bounds__(TPB, 4) void knn_kernel(
        const float* __restrict__ x,
        const int* __restrict__ pid,
        const float* __restrict__ sqf,
        float* __restrict__ out_src,
        float* __restrict__ out_dst,
        float* __restrict__ out_y,
        float* __restrict__ out_ef,
        float* __restrict__ out_mask) {
    __shared__ unsigned int hist[QQ][HIST];           // 16 KB
    __shared__ unsigned short list[QQ][LIST_MAX];     // 8 KB  (j only)
    __shared__ unsigned int cand_key[QQ][CAND_MAX];   // 4 KB
    __shared__ int cand_idx[QQ][CAND_MAX];            // 4 KB
    __shared__ unsigned int wavesum[QQ][TPB / 64];
    __shared__ int s_bsel[QQ];
    __shared__ unsigned int s_listcnt[QQ], s_candcnt[QQ];
    __shared__ int s_fb[QQ];

    const int bid = blockIdx.x;
    const int tid = threadIdx.x;
    const int lane = tid & 63;
    const int w = tid >> 6;
    const int iA = bid * QQ;

    // ---- A: init ----
    for (int t = tid; t < QQ * HIST; t += TPB)
        ((unsigned int*)hist)[t] = 0;
    if (tid < QQ) { s_listcnt[tid] = 0; s_candcnt[tid] = 0; s_bsel[tid] = HIST - 1; }

    float xq[QQ][DD];
    float sq[QQ], Tq[QQ];
#pragma unroll
    for (int q = 0; q < QQ; ++q) {
        const float4* p = reinterpret_cast<const float4*>(x + (iA + q) * DD);
        float4 a0 = p[0], a1 = p[1], a2 = p[2], a3 = p[3];
        xq[q][0]=a0.x; xq[q][1]=a0.y; xq[q][2]=a0.z; xq[q][3]=a0.w;
        xq[q][4]=a1.x; xq[q][5]=a1.y; xq[q][6]=a1.z; xq[q][7]=a1.w;
        xq[q][8]=a2.x; xq[q][9]=a2.y; xq[q][10]=a2.z; xq[q][11]=a2.w;
        xq[q][12]=a3.x; xq[q][13]=a3.y; xq[q][14]=a3.z; xq[q][15]=a3.w;
        sq[q] = sqf[iA + q];
        // adaptive cut: ~3.6% quantile of noncentral chi2_16(r^2) (Gaussian approx)
        Tq[q] = 16.0f + sq[q] - 1.8f * sqrtf(32.0f + 4.0f * sq[q]);
    }
    __syncthreads();

    // ---- B: single scan; sub-threshold points -> j-only list (lean hot loop) ----
    for (int j = tid; j < NN; j += TPB) {
        const float4* xj4 = reinterpret_cast<const float4*>(x + j * DD);
        float4 a0 = xj4[0], a1 = xj4[1], a2 = xj4[2], a3 = xj4[3];
        float xj[DD] = {a0.x, a0.y, a0.z, a0.w, a1.x, a1.y, a1.z, a1.w,
                        a2.x, a2.y, a2.z, a2.w, a3.x, a3.y, a3.z, a3.w};
        const float sj = sqf[j];
#pragma unroll
        for (int q = 0; q < QQ; ++q) {
            float d2 = d2_of(xq[q], xj, sq[q], sj);
            if (d2 < Tq[q] && j != iA + q) {
                unsigned int pos = atomicAdd(&s_listcnt[q], 1u);
                if (pos < LIST_MAX) list[q][pos] = (unsigned short)j;
            }
        }
    }
    __syncthreads();

    // ---- C: flags ----
    if (tid < QQ)
        s_fb[tid] = (s_listcnt[tid] < KK) || (s_listcnt[tid] > LIST_MAX);
    __syncthreads();
    const int anyfb = s_fb[0] | s_fb[1] | s_fb[2] | s_fb[3];

    // ---- D: (rare) fallback rescan: full-range hist for flagged queries ----
    if (anyfb) {
        for (int j = tid; j < NN; j += TPB) {
            const float4* xj4 = reinterpret_cast<const float4*>(x + j * DD);
            float4 a0 = xj4[0], a1 = xj4[1], a2 = xj4[2], a3 = xj4[3];
            float xj[DD] = {a0.x, a0.y, a0.z, a0.w, a1.x, a1.y, a1.z, a1.w,
                            a2.x, a2.y, a2.z, a2.w, a3.x, a3.y, a3.z, a3.w};
            const float sj = sqf[j];
#pragma unroll
            for (int q = 0; q < QQ; ++q) {
                if (s_fb[q] && j != iA + q) {
                    float d2 = d2_of(xq[q], xj, sq[q], sj);
                    atomicAdd(&hist[q][bucket_of(d2)], 1u);
                }
            }
        }
    }

    // ---- E: fast-path hist from list entries (recompute d2, bit-identical) ----
#pragma unroll
    for (int q = 0; q < QQ; ++q) {
        if (!s_fb[q]) {
            const int lc = (int)s_listcnt[q];
            for (int e = tid; e < lc; e += TPB) {
                const int j = list[q][e];
                const float4* xj4 = reinterpret_cast<const float4*>(x + j * DD);
                float4 a0 = xj4[0], a1 = xj4[1], a2 = xj4[2], a3 = xj4[3];
                float xj[DD] = {a0.x, a0.y, a0.z, a0.w, a1.x, a1.y, a1.z, a1.w,
                                a2.x, a2.y, a2.z, a2.w, a3.x, a3.y, a3.z, a3.w};
                float d2 = d2_of(xq[q], xj, sq[q], sqf[j]);
                atomicAdd(&hist[q][bucket_of(d2)], 1u);
            }
        }
    }
    __syncthreads();

    // ---- F: prefix-scan over buckets -> bucket of the 64th key (r8-validated) ----
    {
        unsigned int local[QQ], inc[QQ];
#pragma unroll
        for (int q = 0; q < QQ; ++q) {
            const int b0 = tid * (HIST / TPB);          // 2 buckets per thread
            unsigned int s = 0;
#pragma unroll
            for (int b = 0; b < HIST / TPB; ++b) s += hist[q][b0 + b];
            local[q] = s;
            unsigned int v = s;
#pragma unroll
            for (int off = 1; off < 64; off <<= 1) {
                unsigned int n = __shfl_up(v, off, 64);
                if (lane >= off) v += n;
            }
            inc[q] = v;
        }
        if (lane == 63)
#pragma unroll
            for (int q = 0; q < QQ; ++q) wavesum[q][w] = inc[q];
        __syncthreads();
#pragma unroll
        for (int q = 0; q < QQ; ++q) {
            unsigned int woff = 0;
            for (int ww = 0; ww < w; ++ww) woff += wavesum[q][ww];
            unsigned int cum = inc[q] + woff;
            unsigned int prev = cum - local[q];
            if (prev < KK && KK <= cum) {                // unique thread
                unsigned int acc = prev;
                int b = tid * (HIST / TPB);
                while (acc + hist[q][b] < KK) { acc += hist[q][b]; ++b; }
                s_bsel[q] = b;
            }
        }
    }
    __syncthreads();

    // ---- G: candidate gather ----
    // fast path: from list (bucket <= bsel), recompute exact d2 (bit-identical)
#pragma unroll
    for (int q = 0; q < QQ; ++q) {
        if (!s_fb[q]) {
            const int bsel = s_bsel[q];
            const int lc = (int)s_listcnt[q];
            for (int e = tid; e < lc; e += TPB) {
                const int j = list[q][e];
                const float4* xj4 = reinterpret_cast<const float4*>(x + j * DD);
                float4 a0 = xj4[0], a1 = xj4[1], a2 = xj4[2], a3 = xj4[3];
                float xj[DD] = {a0.x, a0.y, a0.z, a0.w, a1.x, a1.y, a1.z, a1.w,
                                a2.x, a2.y, a2.z, a2.w, a3.x, a3.y, a3.z, a3.w};
                float d2 = d2_of(xq[q], xj, sq[q], sqf[j]);
                if (bucket_of(d2) <= bsel) {
                    unsigned int pos = atomicAdd(&s_candcnt[q], 1u);
                    if (pos < CAND_MAX) {
                        unsigned int u = __float_as_uint(d2);
                        u ^= (u & 0x80000000u) ? 0xFFFFFFFFu : 0x80000000u;
                        cand_key[q][pos] = u;
                        cand_idx[q][pos] = j;
                    }
                }
            }
        }
    }
    // fallback: full scan (r8-validated semantics)
    if (anyfb) {
        for (int j = tid; j < NN; j += TPB) {
            const float4* xj4 = reinterpret_cast<const float4*>(x + j * DD);
            float4 a0 = xj4[0], a1 = xj4[1], a2 = xj4[2], a3 = xj4[3];
            float xj[DD] = {a0.x, a0.y, a0.z, a0.w, a1.x, a1.y, a1.z, a1.w,
                            a2.x, a2.y, a2.z, a2.w, a3.x, a3.y, a3.z, a3.w};
            const float sj = sqf[j];
#pragma unroll
            for (int q = 0; q < QQ; ++q) {
                if (s_fb[q] && j != iA + q) {
                    float d2 = d2_of(xq[q], xj, sq[q], sj);
                    if (bucket_of(d2) <= s_bsel[q]) {
                        unsigned int pos = atomicAdd(&s_candcnt[q], 1u);
                        if (pos < CAND_MAX) {
                            unsigned int u = __float_as_uint(d2);
                            u ^= (u & 0x80000000u) ? 0xFFFFFFFFu : 0x80000000u;
                            cand_key[q][pos] = u;
                            cand_idx[q][pos] = j;
                        }
                    }
                }
            }
        }
    }
    __syncthreads();

    // ---- H: rank by (key asc, index asc) + write outputs (VALIDATED) ----
    for (int q = 0; q < QQ; ++q) {
        const int iq = iA + q;
        const int mypid = pid[iq];
        int c = (int)s_candcnt[q];
        if (c > CAND_MAX) c = CAND_MAX;
        for (int t = tid; t < c; t += TPB) {
            const unsigned int kt = cand_key[q][t];
            const int jt = cand_idx[q][t];
            int rank = 0;
            for (int u = 0; u < c; ++u) {
                unsigned int ku = cand_key[q][u];
                rank += (ku < kt) || (ku == kt && cand_idx[q][u] < jt);
            }
            if (rank < KK) {
                const long e = (long)iq * KK + rank;
                out_src[e] = (float)jt;

                const float* xj = x + jt * DD;
                float diff[DD], sum[DD];
#pragma unroll
                for (int d = 0; d < DD; ++d) {
                    float a = xj[d], b = xq[q][d];
                    diff[d] = __fsub_rn(a, b);   // x_src - x_dst
                    sum[d]  = __fadd_rn(a, b);   // x_src + x_dst
                }
                const float s2 = halving_sumsq16(diff);    // VALIDATED tree
                const bool m = __fsqrt_rn(s2) < 6.0f;
                out_mask[e] = m ? 1.0f : 0.0f;
                const int pj = pid[jt];
                out_y[e] = (m && pj == mypid && pj > 0) ? 1.0f : 0.0f;

                float* ef = out_ef + e * (2 * DD);
#pragma unroll
                for (int d = 0; d < DD; ++d) ef[d] = m ? diff[d] : 0.0f;
#pragma unroll
                for (int d = 0; d < DD; ++d) ef[DD + d] = m ? sum[d] : 0.0f;
            }
        }
    }

    // dst column of edge_index
    for (int t = tid; t < QQ * KK; t += TPB) {
        out_dst[(long)iA * KK + t] = (float)(iA + t / KK);
    }
}

extern "C" void kernel_launch(void* const* d_in, const int* in_sizes, int n_in,
                              void* d_out, int out_size, void* d_ws, size_t ws_size,
                              hipStream_t stream) {
    const float* x = (const float*)d_in[0];
    const int* pid = (const int*)d_in[1];
    float* out = (float*)d_out;

    float* out_x   = out;                                // N*D
    float* out_src = out_x + NN * DD;                    // N*K
    float* out_dst = out_src + NN * KK;                  // N*K
    float* out_y   = out_dst + NN * KK;                  // N*K
    float* out_ef  = out_y + NN * KK;                    // N*K*2D
    float* out_mask = out_ef + (long)NN * KK * 2 * DD;   // N*K

    float* sqf = (float*)d_ws;                           // 16384 f32 = 64 KB

    prep_kernel<<<NN / 256, 256, 0, stream>>>(x, out_x, sqf);
    knn_kernel<<<NN / QQ, TPB, 0, stream>>>(x, pid, sqf, out_src, out_dst,
                                            out_y, out_ef, out_mask);
}

// Round 11
// 394.391 us; speedup vs baseline: 1.0829x; 1.0829x over previous
//
#include <hip/hip_runtime.h>

#define NN 16384
#define DD 16
#define KK 64
#define QQ 4            // queries per block (share x_j loads; queries live in SGPRs)
#define TPB 256
#define HIST 1024       // buckets over d2 in [0,256), width 1/4 — covers ALL pairs
#define HISTW (HIST/2)  // packed: 2 u16 counters per u32
#define LIST_MAX 1024
#define CAND_MAX 256

// XLA:CPU vectorized row-reduce, minor dim 16: lane halving tree. (VALIDATED r5)
__device__ __forceinline__ float halving_sumsq16(const float* v) {
    float p[16];
#pragma unroll
    for (int d = 0; d < 16; ++d) p[d] = __fmul_rn(v[d], v[d]);
    float r8[8];
#pragma unroll
    for (int j = 0; j < 8; ++j) r8[j] = __fadd_rn(p[j], p[j + 8]);
    float r4[4];
#pragma unroll
    for (int j = 0; j < 4; ++j) r4[j] = __fadd_rn(r8[j], r8[j + 4]);
    float r2[2];
#pragma unroll
    for (int j = 0; j < 2; ++j) r2[j] = __fadd_rn(r4[j], r4[j + 2]);
    return __fadd_rn(r2[0], r2[1]);
}

// d2 recipe (VALIDATED r5): f32( f32(sqi+sqj) - 2*dot ), dot = ascending-k fmaf
__device__ __forceinline__ float d2_of(const float* xi, const float* xj,
                                       float sqi, float sqj) {
    float dot = 0.0f;
#pragma unroll
    for (int d = 0; d < DD; ++d) dot = fmaf(xi[d], xj[d], dot);
    return __fsub_rn(__fadd_rn(sqi, sqj), __fmul_rn(2.0f, dot));
}

__device__ __forceinline__ int bucket_of(float d2) {
    int b = (int)__fmul_rn(d2, 4.0f);
    if (b < 0) b = 0;
    if (b >= HIST) b = HIST - 1;
    return b;
}

// ---------------- prep: f32 squared norms (halving tree) + copy x ----------------
__global__ void prep_kernel(const float* __restrict__ x,
                            float* __restrict__ out_x,
                            float* __restrict__ sqf) {
    int i = blockIdx.x * blockDim.x + threadIdx.x;
    if (i < NN) {
        float v[DD];
#pragma unroll
        for (int d = 0; d < DD; ++d) v[d] = x[i * DD + d];
        sqf[i] = halving_sumsq16(v);
    }
    for (int t = i; t < NN * DD; t += gridDim.x * blockDim.x) {
        out_x[t] = x[t];
    }
}

// ---------------- main: 4 queries/block, single scan + ballot append ----------------
__global__ __launch_bounds__(TPB) void knn_kernel(
        const float* __restrict__ x,
        const int* __restrict__ pid,
        const float* __restrict__ sqf,
        float* __restrict__ out_src,
        float* __restrict__ out_dst,
        float* __restrict__ out_y,
        float* __restrict__ out_ef,
        float* __restrict__ out_mask) {
    __shared__ unsigned int hist[QQ][HISTW];          // 8 KB (packed 2x u16)
    __shared__ unsigned short list[QQ][LIST_MAX];     // 8 KB (j only)
    __shared__ unsigned int cand_key[QQ][CAND_MAX];   // 4 KB
    __shared__ int cand_idx[QQ][CAND_MAX];            // 4 KB
    __shared__ unsigned int wavesum[QQ][TPB / 64];
    __shared__ int s_bsel[QQ];
    __shared__ unsigned int s_listcnt[QQ], s_candcnt[QQ];
    __shared__ int s_fb[QQ];

    const int bid = blockIdx.x;
    const int tid = threadIdx.x;
    const int lane = tid & 63;
    const int w = tid >> 6;
    const int iA = bid * QQ;

    // ---- A: init ----
    for (int t = tid; t < QQ * HISTW; t += TPB)
        ((unsigned int*)hist)[t] = 0;
    if (tid < QQ) { s_listcnt[tid] = 0; s_candcnt[tid] = 0; s_bsel[tid] = HIST - 1; }

    float xq[QQ][DD];
    float sq[QQ], Tq[QQ];
#pragma unroll
    for (int q = 0; q < QQ; ++q) {
        const float4* p = reinterpret_cast<const float4*>(x + (iA + q) * DD);
        float4 a0 = p[0], a1 = p[1], a2 = p[2], a3 = p[3];
        xq[q][0]=a0.x; xq[q][1]=a0.y; xq[q][2]=a0.z; xq[q][3]=a0.w;
        xq[q][4]=a1.x; xq[q][5]=a1.y; xq[q][6]=a1.z; xq[q][7]=a1.w;
        xq[q][8]=a2.x; xq[q][9]=a2.y; xq[q][10]=a2.z; xq[q][11]=a2.w;
        xq[q][12]=a3.x; xq[q][13]=a3.y; xq[q][14]=a3.z; xq[q][15]=a3.w;
        sq[q] = sqf[iA + q];
        // adaptive cut: ~3% quantile of noncentral chi2_16(r^2) (Gaussian approx).
        // Self (d2~0) always passes (Tq >= ~5.8). Correctness guarded by fallback.
        Tq[q] = 16.0f + sq[q] - 1.8f * sqrtf(32.0f + 4.0f * sq[q]);
    }
    __syncthreads();

    // ---- B: single scan; d2 < Tq -> ballot-aggregated list append (self included) ----
    for (int j = tid; j < NN; j += TPB) {
        const float4* xj4 = reinterpret_cast<const float4*>(x + j * DD);
        float4 a0 = xj4[0], a1 = xj4[1], a2 = xj4[2], a3 = xj4[3];
        float xj[DD] = {a0.x, a0.y, a0.z, a0.w, a1.x, a1.y, a1.z, a1.w,
                        a2.x, a2.y, a2.z, a2.w, a3.x, a3.y, a3.z, a3.w};
        const float sj = sqf[j];
#pragma unroll
        for (int q = 0; q < QQ; ++q) {
            float d2 = d2_of(xq[q], xj, sq[q], sj);
            bool want = d2 < Tq[q];
            unsigned long long m = __ballot(want);
            if (want) {
                int leader = __ffsll(m) - 1;
                unsigned int base = 0;
                if (lane == leader)
                    base = atomicAdd(&s_listcnt[q], (unsigned int)__popcll(m));
                base = __shfl(base, leader, 64);
                unsigned int pos =
                    base + (unsigned int)__popcll(m & ((1ull << lane) - 1ull));
                if (pos < LIST_MAX) list[q][pos] = (unsigned short)j;
            }
        }
    }
    __syncthreads();

    // ---- C: flags (need KK real neighbors + self = KK+1 entries) ----
    if (tid < QQ)
        s_fb[tid] = (s_listcnt[tid] < KK + 1) || (s_listcnt[tid] > LIST_MAX);
    __syncthreads();
    const int anyfb = s_fb[0] | s_fb[1] | s_fb[2] | s_fb[3];

    // ---- D: (rare) fallback rescan: full hist, self excluded ----
    if (anyfb) {
        for (int j = tid; j < NN; j += TPB) {
            const float4* xj4 = reinterpret_cast<const float4*>(x + j * DD);
            float4 a0 = xj4[0], a1 = xj4[1], a2 = xj4[2], a3 = xj4[3];
            float xj[DD] = {a0.x, a0.y, a0.z, a0.w, a1.x, a1.y, a1.z, a1.w,
                            a2.x, a2.y, a2.z, a2.w, a3.x, a3.y, a3.z, a3.w};
            const float sj = sqf[j];
#pragma unroll
            for (int q = 0; q < QQ; ++q) {
                if (s_fb[q] && j != iA + q) {
                    float d2 = d2_of(xq[q], xj, sq[q], sj);
                    int b = bucket_of(d2);
                    atomicAdd(&hist[q][b >> 1], 1u << ((b & 1) << 4));
                }
            }
        }
    }

    // ---- E: fast-path hist from list (recompute d2, bit-identical; self included) ----
#pragma unroll
    for (int q = 0; q < QQ; ++q) {
        if (!s_fb[q]) {
            const int lc = (int)s_listcnt[q];
            for (int e = tid; e < lc; e += TPB) {
                const int j = list[q][e];
                const float4* xj4 = reinterpret_cast<const float4*>(x + j * DD);
                float4 a0 = xj4[0], a1 = xj4[1], a2 = xj4[2], a3 = xj4[3];
                float xj[DD] = {a0.x, a0.y, a0.z, a0.w, a1.x, a1.y, a1.z, a1.w,
                                a2.x, a2.y, a2.z, a2.w, a3.x, a3.y, a3.z, a3.w};
                float d2 = d2_of(xq[q], xj, sq[q], sqf[j]);
                int b = bucket_of(d2);
                atomicAdd(&hist[q][b >> 1], 1u << ((b & 1) << 4));
            }
        }
    }
    __syncthreads();

    // ---- F: prefix-scan over packed buckets -> bucket of need-th key ----
    {
        unsigned int local[QQ], inc[QQ];
        unsigned int pc0[QQ], pc1[QQ], pc2[QQ], pc3[QQ];
#pragma unroll
        for (int q = 0; q < QQ; ++q) {
            unsigned int h0 = hist[q][2 * tid];
            unsigned int h1 = hist[q][2 * tid + 1];
            pc0[q] = h0 & 0xFFFFu; pc1[q] = h0 >> 16;
            pc2[q] = h1 & 0xFFFFu; pc3[q] = h1 >> 16;
            unsigned int s = pc0[q] + pc1[q] + pc2[q] + pc3[q];
            local[q] = s;
            unsigned int v = s;
#pragma unroll
            for (int off = 1; off < 64; off <<= 1) {
                unsigned int n = __shfl_up(v, off, 64);
                if (lane >= off) v += n;
            }
            inc[q] = v;
        }
        if (lane == 63)
#pragma unroll
            for (int q = 0; q < QQ; ++q) wavesum[q][w] = inc[q];
        __syncthreads();
#pragma unroll
        for (int q = 0; q < QQ; ++q) {
            const unsigned int need = s_fb[q] ? KK : (KK + 1);
            unsigned int woff = 0;
            for (int ww = 0; ww < w; ++ww) woff += wavesum[q][ww];
            unsigned int cum = inc[q] + woff;          // buckets [0, 4t+4)
            unsigned int prev = cum - local[q];        // buckets [0, 4t)
            if (prev < need && need <= cum) {          // unique thread
                unsigned int acc = prev;
                int b = 4 * tid;
                if (acc + pc0[q] < need) { acc += pc0[q]; ++b;
                    if (acc + pc1[q] < need) { acc += pc1[q]; ++b;
                        if (acc + pc2[q] < need) { acc += pc2[q]; ++b; } } }
                s_bsel[q] = b;
            }
        }
    }
    __syncthreads();

    // ---- G: candidate gather (self excluded here) ----
#pragma unroll
    for (int q = 0; q < QQ; ++q) {
        if (!s_fb[q]) {
            const int bsel = s_bsel[q];
            const int lc = (int)s_listcnt[q];
            for (int e = tid; e < lc; e += TPB) {
                const int j = list[q][e];
                const float4* xj4 = reinterpret_cast<const float4*>(x + j * DD);
                float4 a0 = xj4[0], a1 = xj4[1], a2 = xj4[2], a3 = xj4[3];
                float xj[DD] = {a0.x, a0.y, a0.z, a0.w, a1.x, a1.y, a1.z, a1.w,
                                a2.x, a2.y, a2.z, a2.w, a3.x, a3.y, a3.z, a3.w};
                float d2 = d2_of(xq[q], xj, sq[q], sqf[j]);
                if (bucket_of(d2) <= bsel && j != iA + q) {
                    unsigned int pos = atomicAdd(&s_candcnt[q], 1u);
                    if (pos < CAND_MAX) {
                        unsigned int u = __float_as_uint(d2);
                        u ^= (u & 0x80000000u) ? 0xFFFFFFFFu : 0x80000000u;
                        cand_key[q][pos] = u;
                        cand_idx[q][pos] = j;
                    }
                }
            }
        }
    }
    if (anyfb) {
        for (int j = tid; j < NN; j += TPB) {
            const float4* xj4 = reinterpret_cast<const float4*>(x + j * DD);
            float4 a0 = xj4[0], a1 = xj4[1], a2 = xj4[2], a3 = xj4[3];
            float xj[DD] = {a0.x, a0.y, a0.z, a0.w, a1.x, a1.y, a1.z, a1.w,
                            a2.x, a2.y, a2.z, a2.w, a3.x, a3.y, a3.z, a3.w};
            const float sj = sqf[j];
#pragma unroll
            for (int q = 0; q < QQ; ++q) {
                if (s_fb[q] && j != iA + q) {
                    float d2 = d2_of(xq[q], xj, sq[q], sj);
                    if (bucket_of(d2) <= s_bsel[q]) {
                        unsigned int pos = atomicAdd(&s_candcnt[q], 1u);
                        if (pos < CAND_MAX) {
                            unsigned int u = __float_as_uint(d2);
                            u ^= (u & 0x80000000u) ? 0xFFFFFFFFu : 0x80000000u;
                            cand_key[q][pos] = u;
                            cand_idx[q][pos] = j;
                        }
                    }
                }
            }
        }
    }
    __syncthreads();

    // ---- H: rank by (key asc, index asc) + write outputs (VALIDATED) ----
    for (int q = 0; q < QQ; ++q) {
        const int iq = iA + q;
        const int mypid = pid[iq];
        int c = (int)s_candcnt[q];
        if (c > CAND_MAX) c = CAND_MAX;
        for (int t = tid; t < c; t += TPB) {
            const unsigned int kt = cand_key[q][t];
            const int jt = cand_idx[q][t];
            int rank = 0;
            for (int u = 0; u < c; ++u) {
                unsigned int ku = cand_key[q][u];
                rank += (ku < kt) || (ku == kt && cand_idx[q][u] < jt);
            }
            if (rank < KK) {
                const long e = (long)iq * KK + rank;
                out_src[e] = (float)jt;

                const float* xj = x + jt * DD;
                float diff[DD], sum[DD];
#pragma unroll
                for (int d = 0; d < DD; ++d) {
                    float a = xj[d], b = xq[q][d];
                    diff[d] = __fsub_rn(a, b);   // x_src - x_dst
                    sum[d]  = __fadd_rn(a, b);   // x_src + x_dst
                }
                const float s2 = halving_sumsq16(diff);    // VALIDATED tree
                const bool m = __fsqrt_rn(s2) < 6.0f;
                out_mask[e] = m ? 1.0f : 0.0f;
                const int pj = pid[jt];
                out_y[e] = (m && pj == mypid && pj > 0) ? 1.0f : 0.0f;

                float* ef = out_ef + e * (2 * DD);
#pragma unroll
                for (int d = 0; d < DD; ++d) ef[d] = m ? diff[d] : 0.0f;
#pragma unroll
                for (int d = 0; d < DD; ++d) ef[DD + d] = m ? sum[d] : 0.0f;
            }
        }
    }

    // dst column of edge_index
    for (int t = tid; t < QQ * KK; t += TPB) {
        out_dst[(long)iA * KK + t] = (float)(iA + t / KK);
    }
}

extern "C" void kernel_launch(void* const* d_in, const int* in_sizes, int n_in,
                              void* d_out, int out_size, void* d_ws, size_t ws_size,
                              hipStream_t stream) {
    const float* x = (const float*)d_in[0];
    const int* pid = (const int*)d_in[1];
    float* out = (float*)d_out;

    float* out_x   = out;                                // N*D
    float* out_src = out_x + NN * DD;                    // N*K
    float* out_dst = out_src + NN * KK;                  // N*K
    float* out_y   = out_dst + NN * KK;                  // N*K
    float* out_ef  = out_y + NN * KK;                    // N*K*2D
    float* out_mask = out_ef + (long)NN * KK * 2 * DD;   // N*K

    float* sqf = (float*)d_ws;                           // 16384 f32 = 64 KB

    prep_kernel<<<NN / 256, 256, 0, stream>>>(x, out_x, sqf);
    knn_kernel<<<NN / QQ, TPB, 0, stream>>>(x, pid, sqf, out_src, out_dst,
                                            out_y, out_ef, out_mask);
}